// Round 3
// baseline (98.118 us; speedup 1.0000x reference)
//
#include <hip/hip_runtime.h>

// FAVOR+ causal linear attention, chunk-parallel bf16 MFMA, C=32.
// P0 (257 blk): Q,K -> bf16 [n][d] transposes; F -> bf16.
// P1 (512 blk): per 32-chunk: phiQ^T(ws), phiK^T, phiK, S_c^T(ws), z_c(ws),
//               masked Amat, norm_intra(ws), Y_intra = Amat.V (ws fp32).
// P2 (260 blk): exclusive prefix scan of S^T (bf16) and z (fp32) over 64 chunks.
// P3 (512 blk): out = (phiQ^T.S_excl + Y_intra) / (norm_intra + phiQ^T.z_excl).

#define BH 8
#define DD 64
#define DV 64
#define NSEQ 2048
#define MM 128
#define CK 32
#define NCH (NSEQ / CK)   // 64
#define PHI_SCALE 0.08838834764831845f

typedef unsigned int uint;
typedef unsigned short ushort;
typedef __attribute__((ext_vector_type(8))) short bf16x8;
typedef __attribute__((ext_vector_type(4))) float f32x4;
#define MFMA16(a, b, c) __builtin_amdgcn_mfma_f32_16x16x32_bf16((a), (b), (c), 0, 0, 0)

__device__ __forceinline__ short f2bf(float x) {
    uint u = __float_as_uint(x);
    u += 0x7fffu + ((u >> 16) & 1u);
    return (short)(u >> 16);
}
__device__ __forceinline__ float bf2f(ushort b) {
    return __uint_as_float(((uint)b) << 16);
}

// ws byte offsets
#define OFF_QT   0u                      // bf16 [BH][2048][64]   2 MB
#define OFF_KT   2097152u                // bf16 [BH][2048][64]   2 MB
#define OFF_FB   4194304u                // bf16 [128][64]        16 KB
#define OFF_PQT  4210688u                // bf16 [BH][2048][128]  4 MB
#define OFF_ST   8404992u                // bf16 [BH][64][64][128] 8 MB
#define OFF_Z    16793600u               // f32  [BH][64][128]    256 KB
#define OFF_Y    17055744u               // f32  [BH][2048][64]   4 MB
#define OFF_NI   21250048u               // f32  [BH][2048]       64 KB

// ---------------- P0: transpose Q,K to bf16 [n][d]; convert F ----------------
__global__ __launch_bounds__(256) void favor_p0(
    const float* __restrict__ keys, const float* __restrict__ queries,
    const float* __restrict__ features, ushort* __restrict__ Qt,
    ushort* __restrict__ Kt, ushort* __restrict__ Fb)
{
    const int b = blockIdx.x, tid = threadIdx.x;
    if (b == 256) {  // F: 128x64 fp32 -> bf16, coalesced
        uint* fo = (uint*)Fb;
        const float2* fi = (const float2*)features;
        for (int i = tid; i < 4096; i += 256) {
            float2 f = fi[i];
            fo[i] = (uint)(ushort)f2bf(f.x) | ((uint)(ushort)f2bf(f.y) << 16);
        }
        return;
    }
    const int bh = b >> 5, nc = b & 31, n0 = nc * 64;
    __shared__ short sT[64 * 66];
    for (int pass = 0; pass < 2; ++pass) {
        const float* src = pass ? keys : queries;
        ushort* dst = pass ? Kt : Qt;
        for (int i = tid; i < 4096; i += 256) {
            const int d = i >> 6, n = i & 63;
            sT[d * 66 + n] = f2bf(src[(bh * 64 + d) * NSEQ + n0 + n]);
        }
        __syncthreads();
        uint* dw = (uint*)dst;
        for (int i = tid; i < 2048; i += 256) {
            const int n = i >> 5, dp = i & 31;
            const uint lo = (ushort)sT[(2 * dp) * 66 + n];
            const uint hi = (ushort)sT[(2 * dp + 1) * 66 + n];
            dw[(size_t)(bh * NSEQ + n0 + n) * 32 + dp] = lo | (hi << 16);
        }
        __syncthreads();
    }
}

// ---------------- P1: all scan-independent per-chunk work ----------------
__global__ __launch_bounds__(256) void favor_p1(
    const float* __restrict__ values, const ushort* __restrict__ Qt,
    const ushort* __restrict__ Kt, const ushort* __restrict__ Fb,
    ushort* __restrict__ phiQT, ushort* __restrict__ St,
    float* __restrict__ z, float* __restrict__ Yw, float* __restrict__ normI)
{
    const int bh = blockIdx.x >> 6, ck = blockIdx.x & 63, n0 = ck * CK;
    const int tid = threadIdx.x;
    const int lane = tid & 63, wid = tid >> 6, quad = lane >> 4, l16 = lane & 15;

    __shared__ __align__(16) short sPQT[32 * 136];  // phiQ^T [n][m]
    __shared__ __align__(16) short sPKT[32 * 136];  // phiK^T [n][m]
    __shared__ __align__(16) short sPK[128 * 40];   // phiK   [m][n]
    __shared__ __align__(16) short sV[64 * 40];     // V bf16 [v][j]
    __shared__ __align__(16) short sAm[32 * 40];    // Amat   [n][j]
    __shared__ float sNI[64];

    // stage V chunk (coalesced fp32 rows)
    for (int i = tid; i < 2048; i += 256) {
        const int v = i >> 5, j = i & 31;
        sV[v * 40 + j] = f2bf(values[(bh * DV + v) * NSEQ + n0 + j]);
    }

    // phiQ^T / phiK^T: D[n][m] = sum_d X^T[n][d] * F[m][d]
    {
        const int nt = wid & 1, mg = wid >> 1;
        const ushort* qrow = Qt + (size_t)(bh * NSEQ + n0 + 16 * nt + l16) * 64;
        const ushort* krow = Kt + (size_t)(bh * NSEQ + n0 + 16 * nt + l16) * 64;
        bf16x8 aQ[2], aK[2];
        for (int h = 0; h < 2; ++h) {
            aQ[h] = *(const bf16x8*)(qrow + 32 * h + 8 * quad);
            aK[h] = *(const bf16x8*)(krow + 32 * h + 8 * quad);
        }
        for (int t = 0; t < 4; ++t) {
            const int mt = mg * 4 + t;
            f32x4 accQ = {0.f, 0.f, 0.f, 0.f}, accK = {0.f, 0.f, 0.f, 0.f};
            for (int h = 0; h < 2; ++h) {
                bf16x8 bF = *(const bf16x8*)(Fb + (16 * mt + l16) * 64 + 32 * h + 8 * quad);
                accQ = MFMA16(aQ[h], bF, accQ);
                accK = MFMA16(aK[h], bF, accK);
            }
            for (int r = 0; r < 4; ++r) {
                const int nl = 16 * nt + 4 * quad + r, m = 16 * mt + l16;
                sPQT[nl * 136 + m] = f2bf(fmaxf(accQ[r], 0.f) * PHI_SCALE);
                sPKT[nl * 136 + m] = f2bf(fmaxf(accK[r], 0.f) * PHI_SCALE);
            }
        }
    }
    // phiK [m][n]: D[m][n] = sum_d F[m][d] * K^T[n][d]
    for (int t = 0; t < 2; ++t) {
        const int mt = wid * 2 + t;
        bf16x8 aF[2];
        for (int h = 0; h < 2; ++h)
            aF[h] = *(const bf16x8*)(Fb + (16 * mt + l16) * 64 + 32 * h + 8 * quad);
        for (int ntt = 0; ntt < 2; ++ntt) {
            f32x4 acc = {0.f, 0.f, 0.f, 0.f};
            for (int h = 0; h < 2; ++h) {
                bf16x8 bK = *(const bf16x8*)(Kt + (size_t)(bh * NSEQ + n0 + 16 * ntt + l16) * 64 + 32 * h + 8 * quad);
                acc = MFMA16(aF[h], bK, acc);
            }
            for (int r = 0; r < 4; ++r)
                sPK[(16 * mt + 4 * quad + r) * 40 + 16 * ntt + l16] =
                    f2bf(fmaxf(acc[r], 0.f) * PHI_SCALE);
        }
    }
    __syncthreads();  // B0

    // S_c^T [v][m] = sum_n V[v][n] * phiK[m][n]
    {
        const int vt = wid;
        bf16x8 aV = *(const bf16x8*)(sV + (16 * vt + l16) * 40 + 8 * quad);
        ushort* So = St + (size_t)(bh * NCH + ck) * (DV * MM);
        for (int mt = 0; mt < 8; ++mt) {
            bf16x8 bP = *(const bf16x8*)(sPK + (16 * mt + l16) * 40 + 8 * quad);
            f32x4 acc = {0.f, 0.f, 0.f, 0.f};
            acc = MFMA16(aV, bP, acc);
            for (int r = 0; r < 4; ++r)
                So[(16 * vt + 4 * quad + r) * MM + 16 * mt + l16] = (ushort)f2bf(acc[r]);
        }
    }
    // z_c[m] = sum_n phiK^T[n][m]
    if (tid < 128) {
        float s = 0.f;
        for (int n = 0; n < 32; ++n) s += bf2f((ushort)sPKT[n * 136 + tid]);
        z[(bh * NCH + ck) * MM + tid] = s;
    }
    // phiQ^T dump to ws (uint-packed, coalesced)
    {
        const uint* sp = (const uint*)sPQT;  // row stride 68 uints
        uint* pq = (uint*)(phiQT + (size_t)(bh * NSEQ + n0) * MM);
        for (int i = tid; i < 2048; i += 256) {
            const int n = i >> 6, mp = i & 63;
            pq[n * 64 + mp] = sp[n * 68 + mp];
        }
    }
    // Amat [n][j] = sum_m phiQ^T[n][m] * phiK^T[j][m], causal mask + rowsum
    {
        const int nt = wid & 1, jt = wid >> 1;
        f32x4 acc = {0.f, 0.f, 0.f, 0.f};
        for (int mc = 0; mc < 4; ++mc) {
            bf16x8 aP = *(const bf16x8*)(sPQT + (16 * nt + l16) * 136 + 32 * mc + 8 * quad);
            bf16x8 bP = *(const bf16x8*)(sPKT + (16 * jt + l16) * 136 + 32 * mc + 8 * quad);
            acc = MFMA16(aP, bP, acc);
        }
        float rs[4];
        for (int r = 0; r < 4; ++r) {
            const int nl = 16 * nt + 4 * quad + r, jl = 16 * jt + l16;
            const float av = (jl <= nl) ? acc[r] : 0.f;
            rs[r] = av;
            sAm[nl * 40 + jl] = f2bf(av);
        }
        for (int r = 0; r < 4; ++r) {
            float s = rs[r];
            s += __shfl_xor(s, 1); s += __shfl_xor(s, 2);
            s += __shfl_xor(s, 4); s += __shfl_xor(s, 8);
            if (l16 == 0) sNI[jt * 32 + 16 * nt + 4 * quad + r] = s;
        }
    }
    __syncthreads();  // B1

    // Y_intra [n][v] = Amat . V
    {
        const int nt = wid & 1, vb = (wid >> 1) * 2;
        bf16x8 aA = *(const bf16x8*)(sAm + (16 * nt + l16) * 40 + 8 * quad);
        for (int t = 0; t < 2; ++t) {
            const int vt = vb + t;
            bf16x8 bV = *(const bf16x8*)(sV + (16 * vt + l16) * 40 + 8 * quad);
            f32x4 acc = {0.f, 0.f, 0.f, 0.f};
            acc = MFMA16(aA, bV, acc);
            for (int r = 0; r < 4; ++r) {
                const int nl = 16 * nt + 4 * quad + r, v = 16 * vt + l16;
                Yw[(size_t)(bh * NSEQ + n0 + nl) * DV + v] = acc[r];
            }
        }
    }
    if (tid < 32) normI[bh * NSEQ + n0 + tid] = sNI[tid] + sNI[32 + tid];
}

// ---------------- P2: exclusive prefix scans over 64 chunks ----------------
__global__ __launch_bounds__(256) void favor_p2(ushort* __restrict__ St,
                                                float* __restrict__ z)
{
    const int gid = blockIdx.x * 256 + threadIdx.x;
    if (blockIdx.x < 256) {  // 65536 S^T columns
        const int bh = gid >> 13, vm = gid & 8191;
        ushort* p = St + (size_t)bh * NCH * 8192 + vm;
        float run = 0.f;
        for (int half = 0; half < 2; ++half) {
            float vals[32];
            #pragma unroll
            for (int cc = 0; cc < 32; ++cc) vals[cc] = bf2f(p[(32 * half + cc) * 8192]);
            #pragma unroll
            for (int cc = 0; cc < 32; ++cc) {
                p[(32 * half + cc) * 8192] = (ushort)f2bf(run);
                run += vals[cc];
            }
        }
    } else {  // 1024 z columns
        const int i = gid - 65536;
        if (i < BH * MM) {
            const int bh = i >> 7, m = i & 127;
            float* p = z + bh * NCH * MM + m;
            float run = 0.f;
            for (int half = 0; half < 2; ++half) {
                float vals[32];
                #pragma unroll
                for (int cc = 0; cc < 32; ++cc) vals[cc] = p[(32 * half + cc) * MM];
                #pragma unroll
                for (int cc = 0; cc < 32; ++cc) {
                    p[(32 * half + cc) * MM] = run;
                    run += vals[cc];
                }
            }
        }
    }
}

// ---------------- P3: out = (phiQ^T.S_excl + Y) / (normI + phiQ^T.z_excl) ----
__global__ __launch_bounds__(256) void favor_p3(
    const ushort* __restrict__ phiQT, const ushort* __restrict__ St,
    const float* __restrict__ z, const float* __restrict__ Yw,
    const float* __restrict__ normI, float* __restrict__ out)
{
    const int bh = blockIdx.x >> 6, ck = blockIdx.x & 63, n0 = ck * CK;
    const int tid = threadIdx.x;
    const int lane = tid & 63, wid = tid >> 6, quad = lane >> 4, l16 = lane & 15;

    __shared__ float sOut[32 * 66];
    __shared__ float sPart[32 * 8];
    __shared__ float sNm[32];

    const ushort* pqt = phiQT + (size_t)(bh * NSEQ + n0) * MM;
    const ushort* sb  = St + (size_t)(bh * NCH + ck) * 8192;

    // A2: D[n][v] = phiQ^T . S_excl
    const int nt = wid & 1, vb = (wid >> 1) * 2;
    bf16x8 aP[4];
    for (int mc = 0; mc < 4; ++mc)
        aP[mc] = *(const bf16x8*)(pqt + (16 * nt + l16) * MM + 32 * mc + 8 * quad);
    f32x4 acc[2];
    for (int t = 0; t < 2; ++t) {
        acc[t] = (f32x4){0.f, 0.f, 0.f, 0.f};
        const int vt = vb + t;
        for (int mc = 0; mc < 4; ++mc) {
            bf16x8 bS = *(const bf16x8*)(sb + (16 * vt + l16) * MM + 32 * mc + 8 * quad);
            acc[t] = MFMA16(aP[mc], bS, acc[t]);
        }
    }

    // norm matvec partials: thread (n = t>>3, seg = t&7) does 16 m
    {
        const int n = tid >> 3, seg = tid & 7;
        const uint* pr = (const uint*)(pqt + n * MM + seg * 16);
        const float* zz = z + (bh * NCH + ck) * MM + seg * 16;
        float s = 0.f;
        #pragma unroll
        for (int k = 0; k < 8; ++k) {
            const uint u = pr[k];
            s += bf2f((ushort)(u & 0xffffu)) * zz[2 * k];
            s += bf2f((ushort)(u >> 16)) * zz[2 * k + 1];
        }
        sPart[n * 8 + seg] = s;
    }
    __syncthreads();
    if (tid < 32) {
        float nm = normI[bh * NSEQ + n0 + tid];
        #pragma unroll
        for (int s8 = 0; s8 < 8; ++s8) nm += sPart[tid * 8 + s8];
        sNm[tid] = nm;
    }
    __syncthreads();

    // add Y, divide, transpose-stage
    for (int t = 0; t < 2; ++t) {
        const int vt = vb + t;
        for (int r = 0; r < 4; ++r) {
            const int nl = 16 * nt + 4 * quad + r, v = 16 * vt + l16;
            const float y = Yw[(size_t)(bh * NSEQ + n0 + nl) * DV + v];
            sOut[nl * 66 + v] = (acc[t][r] + y) / sNm[nl];
        }
    }
    __syncthreads();
    for (int i = tid; i < 2048; i += 256) {
        const int v = i >> 5, n = i & 31;
        out[(bh * DV + v) * NSEQ + n0 + n] = sOut[n * 66 + v];
    }
}

extern "C" void kernel_launch(void* const* d_in, const int* in_sizes, int n_in,
                              void* d_out, int out_size, void* d_ws, size_t ws_size,
                              hipStream_t stream)
{
    (void)in_sizes; (void)n_in; (void)out_size; (void)ws_size;
    const float* keys     = (const float*)d_in[0];
    const float* values   = (const float*)d_in[1];
    const float* queries  = (const float*)d_in[2];
    const float* features = (const float*)d_in[3];
    float* outp = (float*)d_out;

    char* ws = (char*)d_ws;
    ushort* Qt    = (ushort*)(ws + OFF_QT);
    ushort* Kt    = (ushort*)(ws + OFF_KT);
    ushort* Fb    = (ushort*)(ws + OFF_FB);
    ushort* phiQT = (ushort*)(ws + OFF_PQT);
    ushort* St    = (ushort*)(ws + OFF_ST);
    float*  z     = (float*)(ws + OFF_Z);
    float*  Yw    = (float*)(ws + OFF_Y);
    float*  nI    = (float*)(ws + OFF_NI);

    favor_p0<<<dim3(257), dim3(256), 0, stream>>>(keys, queries, features, Qt, Kt, Fb);
    favor_p1<<<dim3(512), dim3(256), 0, stream>>>(values, Qt, Kt, Fb, phiQT, St, z, Yw, nI);
    favor_p2<<<dim3(260), dim3(256), 0, stream>>>(St, z);
    favor_p3<<<dim3(512), dim3(256), 0, stream>>>(phiQT, St, z, Yw, nI, outp);
}